// Round 5
// baseline (1753.840 us; speedup 1.0000x reference)
//
#include <hip/hip_runtime.h>
#include <stdint.h>

#define B_ 8
#define D_ 128
#define T_ 4096
#define Q_ 30
#define C_ 1024

typedef __attribute__((ext_vector_type(8))) short short8;
typedef __attribute__((ext_vector_type(4))) float float4_;

// pre-split codebook: per 64-code chunk: 16KB hi bf16 | 16KB lo bf16, XOR-swizzled,
// byte-identical to the LDS image the main loop reads -> staging is a raw DMA copy.
__device__ __align__(16) short g_split[(size_t)Q_*16*16384];

__device__ __forceinline__ unsigned short f2bf(float f){
  unsigned u = __builtin_bit_cast(unsigned, f);
  u += 0x7fffu + ((u>>16)&1u);
  return (unsigned short)(u>>16);
}
__device__ __forceinline__ float bf2f(unsigned short h){
  unsigned u = ((unsigned)h)<<16;
  return __builtin_bit_cast(float, u);
}

typedef __attribute__((address_space(3))) void lds_void;
typedef __attribute__((address_space(1))) const void gbl_void;
__device__ __forceinline__ void gld16(const void* g, void* l){
  __builtin_amdgcn_global_load_lds((gbl_void*)g, (lds_void*)l, 16, 0, 0);
}

// ---------------- prep 1: per-code ||c||^2, fp64 accumulation ----------------
__global__ void rvq_prep(const float* __restrict__ cb, float* __restrict__ sumsq){
  int g    = blockIdx.x*128 + (threadIdx.x>>1);
  int half = threadIdx.x & 1;
  const float* src = cb + (size_t)g*D_ + half*64;
  double s = 0.0;
#pragma unroll
  for (int i=0;i<64;i+=4){
    float4_ f = *(const float4_*)(src+i);
    s += (double)f.x*f.x + (double)f.y*f.y + (double)f.z*f.z + (double)f.w*f.w;
  }
  s += __shfl_xor(s, 1);
  if (!half) sumsq[g] = (float)s;
}

// ---------------- prep 2: build swizzled (hi,lo) bf16 chunk images -----------
__global__ void rvq_split(const float* __restrict__ cb){
  const int bI   = blockIdx.x;            // global chunk id q*16+c, 0..479
  const int tid  = threadIdx.x;
  const int crel = tid>>2, part = tid&3;
  const int swz  = crel & 15;
  const float* src = cb + ((size_t)(bI*64 + crel))*128 + part*32;
  short* dstH = g_split + ((size_t)bI<<14) + (crel<<7);
#pragma unroll
  for (int i=0;i<32;i+=8){
    float4_ f0 = *(const float4_*)(src+i);
    float4_ f1 = *(const float4_*)(src+i+4);
    float ff[8] = {f0.x,f0.y,f0.z,f0.w,f1.x,f1.y,f1.z,f1.w};
    short8 vh, vl;
#pragma unroll
    for (int j=0;j<8;++j){
      unsigned short hb = f2bf(ff[j]);
      vh[j] = (short)hb;
      vl[j] = (short)f2bf(ff[j] - bf2f(hb));
    }
    const int kgs = ((part<<2) + (i>>3)) ^ swz;
    *(short8*)&dstH[kgs<<3]          = vh;
    *(short8*)&dstH[8192 + (kgs<<3)] = vl;
  }
}

// ------- main: 30-step RVQ, code-split wave pairs, dbuf DMA, fp64 state ------
__global__ __launch_bounds__(512,2) void rvq_main(
    const float* __restrict__ x, const float* __restrict__ cb,
    const float* __restrict__ sumsq, double* __restrict__ lossAcc,
    float* __restrict__ out)
{
  __shared__ short sB[2*32768];          // dbuf(64KB) x half(32KB): hi 16KB | lo 16KB
  __shared__ float sCcQ[1024];           // ||c||^2 for current q
  __shared__ float sMa[4][2][32][2];     // [rgrp][half][row][cand] approx score
  __shared__ int   sMj[4][2][32][2];     // matching global code ids

  const int tid  = threadIdx.x;
  const int wv   = tid>>6;
  const int ln   = tid&63;
  const int col  = ln&15;
  const int quad = ln>>4;
  const int hw   = wv>>2;                // code half: 0 or 1
  const int rgrp = wv&3;                 // row group (also staging slab)
  const int blk  = blockIdx.x;
  const int b    = blk>>5;
  const int t0   = ((blk&31)<<7) + (rgrp<<5);

  // residual, fp64, A-fragment distribution: row = rt*16+col, k = kc*32+quad*8+j
  double rmast[2][4][8];
#pragma unroll
  for (int rt=0;rt<2;++rt){
    const int t = t0 + rt*16 + col;
#pragma unroll
    for (int kc=0;kc<4;++kc)
#pragma unroll
      for (int j=0;j<8;++j){
        const int d = kc*32 + quad*8 + j;
        rmast[rt][kc][j] = (double)x[((size_t)b*D_ + d)*T_ + t];
      }
  }

  short8 ah[2][4], al[2][4];
  auto makeAB = [&](){
#pragma unroll
    for (int rt=0;rt<2;++rt)
#pragma unroll
      for (int kc=0;kc<4;++kc){
        short8 h, l;
#pragma unroll
        for (int j=0;j<8;++j){
          float f = (float)rmast[rt][kc][j];
          unsigned short hb = f2bf(f);
          h[j] = (short)hb;
          l[j] = (short)f2bf(f - bf2f(hb));
        }
        ah[rt][kc] = h; al[rt][kc] = l;
      }
  };
  makeAB();

  // wave stages 8KB slab of its half's chunk for pair-step gstep (q*8+ch)
  auto stage = [&](int gstep){
    const int qq = gstep>>3, cc = gstep&7;
    const int chunk = qq*16 + hw*8 + cc;
    const char* gsrc = (const char*)g_split + ((size_t)chunk<<15) + (rgrp<<13) + (ln<<4);
    // BYTE layout must mirror the read side: buffer stride 64KB, half stride 32KB.
    char* ldst = (char*)sB + ((gstep&1)<<16) + (hw<<15) + (rgrp<<13);
#pragma unroll
    for (int it=0; it<8; ++it)
      gld16(gsrc + it*1024, ldst + it*1024);
  };

  // prologue
  for (int i=tid; i<1024; i+=512) sCcQ[i] = sumsq[i];
  stage(0);
  __syncthreads();

  double lossd = 0.0;

  for (int q=0;q<Q_;++q){
    const float* cbq = cb + (size_t)q*C_*D_;

    float m1[2][4], m2[2][4]; int i1[2][4], i2[2][4];
#pragma unroll
    for (int rt=0;rt<2;++rt)
#pragma unroll
      for (int rg=0;rg<4;++rg){
        m1[rt][rg]=3.0e38f; i1[rt][rg]=0;
        m2[rt][rg]=3.0e38f; i2[rt][rg]=0;
      }

    for (int ch=0; ch<8; ++ch){
      const int gstep = q*8 + ch;
      const int nxt   = (gstep+1 < Q_*8) ? gstep+1 : 0;   // dummy at the very end
      stage(nxt);                                         // 8 DMA into buf (gstep+1)&1
      asm volatile("s_waitcnt vmcnt(8)" ::: "memory");    // this step's DMA landed
      asm volatile("s_barrier" ::: "memory");             // all waves see it
      const int bufS = ((gstep&1)<<15) + (hw<<14);        // short offset: buffer + half

#pragma unroll
      for (int itc=0; itc<2; ++itc){
        float4_ acc[2][2];
#pragma unroll
        for (int a=0;a<2;++a)
#pragma unroll
          for (int c=0;c<2;++c) acc[a][c] = (float4_){0.f,0.f,0.f,0.f};
#pragma unroll
        for (int kc=0;kc<4;++kc){
          short8 bh[2], bl[2];
#pragma unroll
          for (int ct=0;ct<2;++ct){
            const int n   = itc*32 + ct*16 + col;
            const int kgs = ((kc<<2) + quad) ^ col;
            bh[ct] = *(const short8*)&sB[bufS + (n<<7) + (kgs<<3)];
            bl[ct] = *(const short8*)&sB[bufS + 8192 + (n<<7) + (kgs<<3)];
          }
#pragma unroll
          for (int rt=0;rt<2;++rt)
#pragma unroll
            for (int ct=0;ct<2;++ct){
              acc[rt][ct] = __builtin_amdgcn_mfma_f32_16x16x32_bf16(ah[rt][kc], bh[ct], acc[rt][ct], 0,0,0);
              acc[rt][ct] = __builtin_amdgcn_mfma_f32_16x16x32_bf16(ah[rt][kc], bl[ct], acc[rt][ct], 0,0,0);
              acc[rt][ct] = __builtin_amdgcn_mfma_f32_16x16x32_bf16(al[rt][kc], bh[ct], acc[rt][ct], 0,0,0);
            }
        }
#pragma unroll
        for (int ct=0;ct<2;++ct){
          const float cc = sCcQ[(hw<<9) + (ch<<6) + itc*32 + ct*16 + col];
          const int cid  = ch*4 + itc*2 + ct;               // code-in-half = cid*16+col
#pragma unroll
          for (int rt=0;rt<2;++rt)
#pragma unroll
            for (int rg=0;rg<4;++rg){
              float s = fmaf(-2.0f, acc[rt][ct][rg], cc);
              if (s < m1[rt][rg]) {
                m2[rt][rg]=m1[rt][rg]; i2[rt][rg]=i1[rt][rg];
                m1[rt][rg]=s;          i1[rt][rg]=cid;
              } else if (s < m2[rt][rg]) {
                m2[rt][rg]=s;          i2[rt][rg]=cid;
              }
            }
        }
      }
      if (ch != 7)
        asm volatile("s_barrier" ::: "memory");  // reads done before next stage overwrites
    }

    // ---- cross-lane top-2 merge over the 16 col-lanes (codes) ----
    float a1[2][4], a2[2][4]; int j1[2][4], j2[2][4];
#pragma unroll
    for (int rt=0;rt<2;++rt)
#pragma unroll
      for (int rg=0;rg<4;++rg){
        a1[rt][rg]=m1[rt][rg]; j1[rt][rg]=(hw<<9)+(i1[rt][rg]<<4)+col;  // global code
        a2[rt][rg]=m2[rt][rg]; j2[rt][rg]=(hw<<9)+(i2[rt][rg]<<4)+col;
      }
#pragma unroll
    for (int mk=1; mk<16; mk<<=1){
#pragma unroll
      for (int rt=0;rt<2;++rt)
#pragma unroll
        for (int rg=0;rg<4;++rg){
          float b1 = __shfl_xor(a1[rt][rg], mk);
          float b2 = __shfl_xor(a2[rt][rg], mk);
          int   k1 = __shfl_xor(j1[rt][rg], mk);
          int   k2 = __shfl_xor(j2[rt][rg], mk);
          float A1=a1[rt][rg], A2=a2[rt][rg]; int J1=j1[rt][rg], J2=j2[rt][rg];
          bool sw  = (b1 < A1) || (b1 == A1 && k1 < J1);
          float w1 = sw ? b1 : A1; int u1 = sw ? k1 : J1;
          float l1 = sw ? A1 : b1; int v1 = sw ? J1 : k1;
          float o2 = sw ? b2 : A2; int ov = sw ? k2 : J2;
          bool t2  = (o2 < l1) || (o2 == l1 && ov < v1);
          a1[rt][rg]=w1; j1[rt][rg]=u1;
          a2[rt][rg]= t2 ? o2 : l1; j2[rt][rg]= t2 ? ov : v1;
        }
    }
    if (col==0){
#pragma unroll
      for (int rt=0;rt<2;++rt)
#pragma unroll
        for (int rg=0;rg<4;++rg){
          const int m = rt*16 + quad*4 + rg;
          sMa[rgrp][hw][m][0] = a1[rt][rg];  sMj[rgrp][hw][m][0] = j1[rt][rg];
          sMa[rgrp][hw][m][1] = a2[rt][rg];  sMj[rgrp][hw][m][1] = j2[rt][rg];
        }
    }
    __syncthreads();

    // ---- merge halves + fp64 exact re-score of top-2, fp64 residual update --
#pragma unroll
    for (int rt=0;rt<2;++rt){
      const int m = rt*16 + col;
      float x1 = sMa[rgrp][0][m][0], x2 = sMa[rgrp][0][m][1];
      int  xj1 = sMj[rgrp][0][m][0], xj2 = sMj[rgrp][0][m][1];
      float y1 = sMa[rgrp][1][m][0], y2 = sMa[rgrp][1][m][1];
      int  yj1 = sMj[rgrp][1][m][0], yj2 = sMj[rgrp][1][m][1];
      bool sw  = (y1 < x1) || (y1 == x1 && yj1 < xj1);
      float w1 = sw ? y1 : x1;  int u1 = sw ? yj1 : xj1;
      float l1 = sw ? x1 : y1;  int v1 = sw ? xj1 : yj1;
      float o2 = sw ? y2 : x2;  int ov = sw ? yj2 : xj2;
      bool t2  = (o2 < l1) || (o2 == l1 && ov < v1);
      const int jj1 = u1;
      const int jj2 = t2 ? ov : v1;

      const float* p1 = cbq + ((size_t)jj1<<7) + (quad<<3);
      const float* p2 = cbq + ((size_t)jj2<<7) + (quad<<3);
      float c1[4][8], c2[4][8];
#pragma unroll
      for (int kc=0;kc<4;++kc){
        float4_ q10 = *(const float4_*)(p1 + kc*32);
        float4_ q11 = *(const float4_*)(p1 + kc*32 + 4);
        float4_ q20 = *(const float4_*)(p2 + kc*32);
        float4_ q21 = *(const float4_*)(p2 + kc*32 + 4);
        c1[kc][0]=q10.x; c1[kc][1]=q10.y; c1[kc][2]=q10.z; c1[kc][3]=q10.w;
        c1[kc][4]=q11.x; c1[kc][5]=q11.y; c1[kc][6]=q11.z; c1[kc][7]=q11.w;
        c2[kc][0]=q20.x; c2[kc][1]=q20.y; c2[kc][2]=q20.z; c2[kc][3]=q20.w;
        c2[kc][4]=q21.x; c2[kc][5]=q21.y; c2[kc][6]=q21.z; c2[kc][7]=q21.w;
      }
      double s1=0.0, s2=0.0;
#pragma unroll
      for (int kc=0;kc<4;++kc)
#pragma unroll
        for (int j=0;j<8;++j){
          double rd  = rmast[rt][kc][j];
          double cd1 = (double)c1[kc][j];
          double cd2 = (double)c2[kc][j];
          s1 += cd1*(cd1 - 2.0*rd);
          s2 += cd2*(cd2 - 2.0*rd);
        }
      s1 += __shfl_xor(s1, 16); s1 += __shfl_xor(s1, 32);
      s2 += __shfl_xor(s2, 16); s2 += __shfl_xor(s2, 32);
      const bool take2 = (s2 < s1) || (s2 == s1 && jj2 < jj1);
#pragma unroll
      for (int kc=0;kc<4;++kc)
#pragma unroll
        for (int j=0;j<8;++j){
          double cw = (double)(take2 ? c2[kc][j] : c1[kc][j]);
          double rn = rmast[rt][kc][j] - cw;
          rmast[rt][kc][j] = rn;
          lossd += rn*rn;
        }
    }
    makeAB();
    if (q+1 < Q_){
      for (int i=tid; i<1024; i+=512) sCcQ[i] = sumsq[(q+1)*1024 + i];
    }
    __syncthreads();   // publishes sCcQ(q+1); full drain guards buffer reuse across q
  }

  // ---- epilogue: quantized = x - r_final (half-0 waves only; pair is duplicate)
  if (hw == 0){
#pragma unroll
    for (int rt=0;rt<2;++rt){
      const int t = t0 + rt*16 + col;
#pragma unroll
      for (int kc=0;kc<4;++kc)
#pragma unroll
        for (int j=0;j<8;++j){
          const int d = kc*32 + quad*8 + j;
          const size_t o = ((size_t)b*D_ + d)*T_ + t;
          out[o] = (float)((double)x[o] - rmast[rt][kc][j]);
        }
    }
#pragma unroll
    for (int mk=1; mk<64; mk<<=1) lossd += __shfl_xor(lossd, mk);
    if (ln==0) atomicAdd(lossAcc, lossd);
  }
}

__global__ void rvq_fin(const double* __restrict__ lossAcc, float* __restrict__ out){
  out[(size_t)B_*D_*T_] = (float)(*lossAcc * (1.0/((double)B_*(double)D_*(double)T_)));
}

extern "C" void kernel_launch(void* const* d_in, const int* in_sizes, int n_in,
                              void* d_out, int out_size, void* d_ws, size_t ws_size,
                              hipStream_t stream) {
  const float* x  = (const float*)d_in[0];   // [B, D, T] fp32
  const float* cb = (const float*)d_in[1];   // [Q, C, D] fp32
  float* out      = (float*)d_out;           // [B*D*T] quantized + [1] loss
  double* lossAcc = (double*)d_ws;
  float*  sumsq   = (float*)((char*)d_ws + 256);   // Q*C floats

  hipMemsetAsync(d_ws, 0, 256, stream);
  rvq_prep <<<Q_*C_/128, 256, 0, stream>>>(cb, sumsq);
  rvq_split<<<Q_*16,     256, 0, stream>>>(cb);
  rvq_main <<<(B_*T_)/128, 512, 0, stream>>>(x, cb, sumsq, lossAcc, out);
  rvq_fin  <<<1, 1, 0, stream>>>(lossAcc, out);
}

// Round 7
// 1730.336 us; speedup vs baseline: 1.0136x; 1.0136x over previous
//
#include <hip/hip_runtime.h>
#include <stdint.h>

#define B_ 8
#define D_ 128
#define T_ 4096
#define Q_ 30
#define C_ 1024

typedef __attribute__((ext_vector_type(8))) short short8;
typedef __attribute__((ext_vector_type(4))) float float4_;

// pre-split codebook: per 64-code chunk: 16KB hi bf16 | 16KB lo bf16, XOR-swizzled,
// byte-identical to the LDS image -> staging is a raw DMA copy.
__device__ __align__(16) short g_split[(size_t)Q_*16*16384];

__device__ __forceinline__ unsigned short f2bf(float f){
  unsigned u = __builtin_bit_cast(unsigned, f);
  u += 0x7fffu + ((u>>16)&1u);
  return (unsigned short)(u>>16);
}
__device__ __forceinline__ float bf2f(unsigned short h){
  unsigned u = ((unsigned)h)<<16;
  return __builtin_bit_cast(float, u);
}

typedef __attribute__((address_space(3))) void lds_void;
typedef __attribute__((address_space(1))) const void gbl_void;
__device__ __forceinline__ void gld16(const void* g, void* l){
  __builtin_amdgcn_global_load_lds((gbl_void*)g, (lds_void*)l, 16, 0, 0);
}

// ---------------- prep 1: per-code ||c||^2 ----------------
__global__ void rvq_prep(const float* __restrict__ cb, float* __restrict__ sumsq){
  int g    = blockIdx.x*128 + (threadIdx.x>>1);
  int half = threadIdx.x & 1;
  const float* src = cb + (size_t)g*D_ + half*64;
  double s = 0.0;
#pragma unroll
  for (int i=0;i<64;i+=4){
    float4_ f = *(const float4_*)(src+i);
    s += (double)f.x*f.x + (double)f.y*f.y + (double)f.z*f.z + (double)f.w*f.w;
  }
  s += __shfl_xor(s, 1);
  if (!half) sumsq[g] = (float)s;
}

// ---------------- prep 2: build swizzled (hi,lo) bf16 chunk images -----------
__global__ void rvq_split(const float* __restrict__ cb){
  const int bI   = blockIdx.x;            // chunk id q*16+c, 0..479
  const int tid  = threadIdx.x;
  const int crel = tid>>2, part = tid&3;
  const int swz  = crel & 15;
  const float* src = cb + ((size_t)(bI*64 + crel))*128 + part*32;
  short* dstH = g_split + ((size_t)bI<<14) + (crel<<7);
#pragma unroll
  for (int i=0;i<32;i+=8){
    float4_ f0 = *(const float4_*)(src+i);
    float4_ f1 = *(const float4_*)(src+i+4);
    float ff[8] = {f0.x,f0.y,f0.z,f0.w,f1.x,f1.y,f1.z,f1.w};
    short8 vh, vl;
#pragma unroll
    for (int j=0;j<8;++j){
      unsigned short hb = f2bf(ff[j]);
      vh[j] = (short)hb;
      vl[j] = (short)f2bf(ff[j] - bf2f(hb));
    }
    const int kgs = ((part<<2) + (i>>3)) ^ swz;
    *(short8*)&dstH[kgs<<3]          = vh;
    *(short8*)&dstH[8192 + (kgs<<3)] = vl;
  }
}

// ------- main: 30-step RVQ, D-split wave pairs (dh), dbuf DMA, fp64 state ----
__global__ __launch_bounds__(512,1) void rvq_main(
    const float* __restrict__ x, const float* __restrict__ cb,
    const float* __restrict__ sumsq, double* __restrict__ lossAcc,
    float* __restrict__ out)
{
  __shared__ short  sB[2*16384];              // 64KB dbuf: per chunk hi 16K | lo 16K
  __shared__ float  sP[8192];                 // 32KB partial acc: [itc][rt][ct][rgrp][lane]x4
  __shared__ float  sCcQ[1024];               // ||c||^2 for current q
  __shared__ int    sIdx[2][128];             // [cand][rgrp*32+row]
  __shared__ double sS[2][4][2][2][16];       // [dh][rgrp][rt][cand][col]

  const int tid  = threadIdx.x;
  const int wv   = tid>>6;
  const int ln   = tid&63;
  const int col  = ln&15;
  const int quad = ln>>4;
  const int dh   = wv>>2;                // D-half: dims dh*64..dh*64+63
  const int rgrp = wv&3;                 // row group (32 rows)
  const int blk  = blockIdx.x;
  const int b    = blk>>5;
  const int t0   = ((blk&31)<<7) + (rgrp<<5);

  // residual fp64, A-frag distribution: row=rt*16+col, dim d = dh*64+kc*32+quad*8+j
  double rmast[2][2][8];
#pragma unroll
  for (int rt=0;rt<2;++rt){
    const int t = t0 + rt*16 + col;
#pragma unroll
    for (int kc=0;kc<2;++kc)
#pragma unroll
      for (int j=0;j<8;++j){
        const int d = dh*64 + kc*32 + quad*8 + j;
        rmast[rt][kc][j] = (double)x[((size_t)b*D_ + d)*T_ + t];
      }
  }

  short8 ah[2][2], al[2][2];
  auto makeAB = [&](){
#pragma unroll
    for (int rt=0;rt<2;++rt)
#pragma unroll
      for (int kc=0;kc<2;++kc){
        short8 h, l;
#pragma unroll
        for (int j=0;j<8;++j){
          float f = (float)rmast[rt][kc][j];
          unsigned short hb = f2bf(f);
          h[j] = (short)hb;
          l[j] = (short)f2bf(f - bf2f(hb));
        }
        ah[rt][kc] = h; al[rt][kc] = l;
      }
  };
  makeAB();

  // all 8 waves cooperatively stage one 32KB chunk (wave slab = 4KB)
  auto stage = [&](int c){
    const char* gsrc = (const char*)g_split + ((size_t)c<<15) + (wv<<12) + (ln<<4);
    char* ldst = (char*)sB + ((c&1)<<15) + (wv<<12) + (ln<<4);
#pragma unroll
    for (int it=0; it<4; ++it)
      gld16(gsrc + it*1024, ldst + it*1024);
  };

  // prologue
  for (int i=tid; i<1024; i+=512) sCcQ[i] = sumsq[i];
  stage(0);
  __syncthreads();

  double lossd = 0.0;

  for (int q=0;q<Q_;++q){
    const float* cbq = cb + (size_t)q*C_*D_;

    float m1[2][4], m2[2][4]; int i1[2][4], i2[2][4];
    if (dh==0){
#pragma unroll
      for (int rt=0;rt<2;++rt)
#pragma unroll
        for (int rg=0;rg<4;++rg){
          m1[rt][rg]=3.0e38f; i1[rt][rg]=0;
          m2[rt][rg]=3.0e38f; i2[rt][rg]=0;
        }
    }

    for (int ch=0; ch<16; ++ch){
      const int c   = q*16 + ch;
      const int nxt = (c+1 < Q_*16) ? c+1 : 0;
      stage(nxt);                                       // 4 DMA into slot (c+1)&1
      asm volatile("s_waitcnt vmcnt(4)" ::: "memory");  // chunk c's DMA landed
      asm volatile("s_barrier" ::: "memory");           // B1: chunk c visible; P slot free
      const int slot = (c&1)<<14;                       // short offset

      float4_ accT[2][2][2];                            // [itc][rt][ct]
#pragma unroll
      for (int itc=0; itc<2; ++itc){
#pragma unroll
        for (int rt=0;rt<2;++rt)
#pragma unroll
          for (int ct=0;ct<2;++ct) accT[itc][rt][ct] = (float4_){0.f,0.f,0.f,0.f};
#pragma unroll
        for (int kc=0;kc<2;++kc){
          const int kgs = ((dh<<3) + (kc<<2) + quad) ^ col;
          short8 bh[2], bl[2];
#pragma unroll
          for (int ct=0;ct<2;++ct){
            const int n = itc*32 + ct*16 + col;
            bh[ct] = *(const short8*)&sB[slot + (n<<7) + (kgs<<3)];
            bl[ct] = *(const short8*)&sB[slot + 8192 + (n<<7) + (kgs<<3)];
          }
#pragma unroll
          for (int rt=0;rt<2;++rt)
#pragma unroll
            for (int ct=0;ct<2;++ct){
              accT[itc][rt][ct] = __builtin_amdgcn_mfma_f32_16x16x32_bf16(ah[rt][kc], bh[ct], accT[itc][rt][ct], 0,0,0);
              accT[itc][rt][ct] = __builtin_amdgcn_mfma_f32_16x16x32_bf16(ah[rt][kc], bl[ct], accT[itc][rt][ct], 0,0,0);
              accT[itc][rt][ct] = __builtin_amdgcn_mfma_f32_16x16x32_bf16(al[rt][kc], bh[ct], accT[itc][rt][ct], 0,0,0);
            }
        }
        if (dh==1){
#pragma unroll
          for (int rt=0;rt<2;++rt)
#pragma unroll
            for (int ct=0;ct<2;++ct){
              const int idx4 = ((((itc*2+rt)*2+ct)*4 + rgrp)*64 + ln)*4;
              *(float4_*)&sP[idx4] = accT[itc][rt][ct];
            }
        }
      }
      asm volatile("s_barrier" ::: "memory");           // B2: publishes P; dbuf reads done

      if (dh==0){
#pragma unroll
        for (int itc=0; itc<2; ++itc)
#pragma unroll
          for (int ct=0;ct<2;++ct){
            const float cc = sCcQ[(ch<<6) + itc*32 + ct*16 + col];
            const int cid  = ch*4 + itc*2 + ct;
#pragma unroll
            for (int rt=0;rt<2;++rt){
              const int idx4 = ((((itc*2+rt)*2+ct)*4 + rgrp)*64 + ln)*4;
              float4_ p = *(const float4_*)&sP[idx4];
#pragma unroll
              for (int rg=0;rg<4;++rg){
                float tot = accT[itc][rt][ct][rg] + p[rg];
                float s = fmaf(-2.0f, tot, cc);
                if (s < m1[rt][rg]) {
                  m2[rt][rg]=m1[rt][rg]; i2[rt][rg]=i1[rt][rg];
                  m1[rt][rg]=s;          i1[rt][rg]=cid;
                } else if (s < m2[rt][rg]) {
                  m2[rt][rg]=s;          i2[rt][rg]=cid;
                }
              }
            }
          }
      }
    }

    // ---- dh0: cross-lane top-2 merge over 16 col-lanes, publish indices ----
    if (dh==0){
      float a1[2][4], a2[2][4]; int j1[2][4], j2[2][4];
#pragma unroll
      for (int rt=0;rt<2;++rt)
#pragma unroll
        for (int rg=0;rg<4;++rg){
          a1[rt][rg]=m1[rt][rg]; j1[rt][rg]=(i1[rt][rg]<<4)+col;
          a2[rt][rg]=m2[rt][rg]; j2[rt][rg]=(i2[rt][rg]<<4)+col;
        }
#pragma unroll
      for (int mk=1; mk<16; mk<<=1){
#pragma unroll
        for (int rt=0;rt<2;++rt)
#pragma unroll
          for (int rg=0;rg<4;++rg){
            float b1 = __shfl_xor(a1[rt][rg], mk);
            float b2 = __shfl_xor(a2[rt][rg], mk);
            int   k1 = __shfl_xor(j1[rt][rg], mk);
            int   k2 = __shfl_xor(j2[rt][rg], mk);
            float A1=a1[rt][rg], A2=a2[rt][rg]; int J1=j1[rt][rg], J2=j2[rt][rg];
            bool sw  = (b1 < A1) || (b1 == A1 && k1 < J1);
            float w1 = sw ? b1 : A1; int u1 = sw ? k1 : J1;
            float l1 = sw ? A1 : b1; int v1 = sw ? J1 : k1;
            float o2 = sw ? b2 : A2; int ov = sw ? k2 : J2;
            bool t2  = (o2 < l1) || (o2 == l1 && ov < v1);
            a1[rt][rg]=w1; j1[rt][rg]=u1;
            a2[rt][rg]= t2 ? o2 : l1; j2[rt][rg]= t2 ? ov : v1;
          }
      }
      if (col==0){
#pragma unroll
        for (int rt=0;rt<2;++rt)
#pragma unroll
          for (int rg=0;rg<4;++rg){
            const int m = rt*16 + quad*4 + rg;
            sIdx[0][(rgrp<<5)+m] = j1[rt][rg];
            sIdx[1][(rgrp<<5)+m] = j2[rt][rg];
          }
      }
    }
    __syncthreads();   // publishes sIdx

    // ---- phase A: per-half fp64 partial rescore of top-2, publish partials --
    int jjA[2][2];
#pragma unroll
    for (int rt=0;rt<2;++rt){
      const int m   = rt*16 + col;
      const int jj1 = sIdx[0][(rgrp<<5)+m];
      const int jj2 = sIdx[1][(rgrp<<5)+m];
      jjA[rt][0]=jj1; jjA[rt][1]=jj2;
      const float* p1 = cbq + ((size_t)jj1<<7) + dh*64 + (quad<<3);
      const float* p2 = cbq + ((size_t)jj2<<7) + dh*64 + (quad<<3);
      double s1=0.0, s2=0.0;
#pragma unroll
      for (int kc=0;kc<2;++kc){
        float4_ q10 = *(const float4_*)(p1 + kc*32);
        float4_ q11 = *(const float4_*)(p1 + kc*32 + 4);
        float4_ q20 = *(const float4_*)(p2 + kc*32);
        float4_ q21 = *(const float4_*)(p2 + kc*32 + 4);
        float f1[8] = {q10.x,q10.y,q10.z,q10.w,q11.x,q11.y,q11.z,q11.w};
        float f2[8] = {q20.x,q20.y,q20.z,q20.w,q21.x,q21.y,q21.z,q21.w};
#pragma unroll
        for (int j=0;j<8;++j){
          double rd  = rmast[rt][kc][j];
          double cd1 = (double)f1[j];
          double cd2 = (double)f2[j];
          s1 += cd1*(cd1 - 2.0*rd);
          s2 += cd2*(cd2 - 2.0*rd);
        }
      }
      s1 += __shfl_xor(s1, 16); s1 += __shfl_xor(s1, 32);
      s2 += __shfl_xor(s2, 16); s2 += __shfl_xor(s2, 32);
      if (quad==0){
        sS[dh][rgrp][rt][0][col] = s1;
        sS[dh][rgrp][rt][1][col] = s2;
      }
    }
    __syncthreads();   // publishes sS

    // ---- phase B: total scores, pick winner, update own rmast half ---------
#pragma unroll
    for (int rt=0;rt<2;++rt){
      const double t1 = sS[0][rgrp][rt][0][col] + sS[1][rgrp][rt][0][col];
      const double t2 = sS[0][rgrp][rt][1][col] + sS[1][rgrp][rt][1][col];
      const int jj1 = jjA[rt][0], jj2 = jjA[rt][1];
      const bool take2 = (t2 < t1) || (t2 == t1 && jj2 < jj1);
      const int jw = take2 ? jj2 : jj1;
      const float* pw = cbq + ((size_t)jw<<7) + dh*64 + (quad<<3);
#pragma unroll
      for (int kc=0;kc<2;++kc){
        float4_ w0 = *(const float4_*)(pw + kc*32);
        float4_ w1 = *(const float4_*)(pw + kc*32 + 4);
        float fw[8] = {w0.x,w0.y,w0.z,w0.w,w1.x,w1.y,w1.z,w1.w};
#pragma unroll
        for (int j=0;j<8;++j){
          double rn = rmast[rt][kc][j] - (double)fw[j];
          rmast[rt][kc][j] = rn;
          lossd += rn*rn;
        }
      }
    }
    makeAB();
    if (q+1 < Q_){
      for (int i=tid; i<1024; i+=512) sCcQ[i] = sumsq[(q+1)*1024 + i];
    }
    __syncthreads();   // publishes sCcQ(q+1); guards sS/sIdx reuse
  }

  // ---- epilogue: quantized = x - r_final (each wave owns its dims) ----
#pragma unroll
  for (int rt=0;rt<2;++rt){
    const int t = t0 + rt*16 + col;
#pragma unroll
    for (int kc=0;kc<2;++kc)
#pragma unroll
      for (int j=0;j<8;++j){
        const int d = dh*64 + kc*32 + quad*8 + j;
        const size_t o = ((size_t)b*D_ + d)*T_ + t;
        out[o] = (float)((double)x[o] - rmast[rt][kc][j]);
      }
  }
#pragma unroll
  for (int mk=1; mk<64; mk<<=1) lossd += __shfl_xor(lossd, mk);
  if (ln==0) atomicAdd(lossAcc, lossd);
}

__global__ void rvq_fin(const double* __restrict__ lossAcc, float* __restrict__ out){
  out[(size_t)B_*D_*T_] = (float)(*lossAcc * (1.0/((double)B_*(double)D_*(double)T_)));
}

extern "C" void kernel_launch(void* const* d_in, const int* in_sizes, int n_in,
                              void* d_out, int out_size, void* d_ws, size_t ws_size,
                              hipStream_t stream) {
  const float* x  = (const float*)d_in[0];   // [B, D, T] fp32
  const float* cb = (const float*)d_in[1];   // [Q, C, D] fp32
  float* out      = (float*)d_out;           // [B*D*T] quantized + [1] loss
  double* lossAcc = (double*)d_ws;
  float*  sumsq   = (float*)((char*)d_ws + 256);   // Q*C floats

  hipMemsetAsync(d_ws, 0, 256, stream);
  rvq_prep <<<Q_*C_/128, 256, 0, stream>>>(cb, sumsq);
  rvq_split<<<Q_*16,     256, 0, stream>>>(cb);
  rvq_main <<<(B_*T_)/128, 512, 0, stream>>>(x, cb, sumsq, lossAcc, out);
  rvq_fin  <<<1, 1, 0, stream>>>(lossAcc, out);
}